// Round 11
// baseline (772.789 us; speedup 1.0000x reference)
//
#include <hip/hip_runtime.h>
#include <math.h>

#define BUCKET_SHIFT 8            // 256 nodes per bucket
#define BUCKET_MASK 255
#define MAXBUCK 640               // supports N <= 163840
#define TILE 8192

typedef __attribute__((ext_vector_type(8))) short bf16x8;
typedef __attribute__((ext_vector_type(4))) float f32x4;

__device__ inline float bf_lo(unsigned u) { return __uint_as_float(u << 16); }
__device__ inline float bf_hi(unsigned u) { return __uint_as_float(u & 0xffff0000u); }
__device__ inline float bf2f(unsigned short s) { return __uint_as_float((unsigned)s << 16); }
__device__ inline unsigned short f2bf(float f) {   // round-to-nearest-even
  unsigned u = __float_as_uint(f);
  return (unsigned short)((u + 0x7fffu + ((u >> 16) & 1u)) >> 16);
}
__device__ inline void acc8(float* a, uint4 v) {
  a[0] += bf_lo(v.x); a[1] += bf_hi(v.x);
  a[2] += bf_lo(v.y); a[3] += bf_hi(v.y);
  a[4] += bf_lo(v.z); a[5] += bf_hi(v.z);
  a[6] += bf_lo(v.w); a[7] += bf_hi(v.w);
}
__device__ inline unsigned pack2(float a, float b) {
  return (unsigned)f2bf(a) | ((unsigned)f2bf(b) << 16);
}

// ---------------- utility ----------------
__global__ void zero_u32(unsigned int* __restrict__ p, int n) {
  int i = blockIdx.x * blockDim.x + threadIdx.x;
  if (i < n) p[i] = 0u;
}

// ---------------- bucketed CSR build (branch-batched via blockIdx.y) ------------
__global__ __launch_bounds__(256) void bucket_count(const int* __restrict__ dst0,
                                                    const int* __restrict__ dst1,
                                                    int* __restrict__ bcnt, int e, int nbuck) {
  int br = blockIdx.y;
  const int* dst = br ? dst1 : dst0;
  bcnt += (size_t)br * nbuck;
  __shared__ int lc[MAXBUCK];
  for (int i = threadIdx.x; i < nbuck; i += 256) lc[i] = 0;
  __syncthreads();
  for (int i = blockIdx.x * blockDim.x + threadIdx.x; i < e; i += gridDim.x * blockDim.x)
    atomicAdd(&lc[dst[i] >> BUCKET_SHIFT], 1);
  __syncthreads();
  for (int i = threadIdx.x; i < nbuck; i += 256)
    if (lc[i]) atomicAdd(&bcnt[i], lc[i]);
}

// rank-based scatter; bucket prefix (bbase) computed locally in LDS
__global__ __launch_bounds__(256) void bucket_scatter(const int* __restrict__ src0,
                                                      const int* __restrict__ dst0,
                                                      const int* __restrict__ src1,
                                                      const int* __restrict__ dst1,
                                                      const int* __restrict__ bcnt,
                                                      int* __restrict__ bcur,
                                                      int* __restrict__ bucketed,
                                                      int e, int nbuck) {
  int br = blockIdx.y;
  const int* src = br ? src1 : src0;
  const int* dst = br ? dst1 : dst0;
  bcnt += (size_t)br * nbuck;
  bcur += (size_t)br * nbuck;
  bucketed += (size_t)br * e;
  __shared__ int sbase[MAXBUCK], lcnt[MAXBUCK], gb[MAXBUCK];
  __shared__ int stmp[256];
  __shared__ int scarry;
  int t = threadIdx.x;
  int tile0 = blockIdx.x * TILE;
  int tn = min(TILE, e - tile0);
  // local exclusive scan of bcnt -> sbase
  if (t == 0) scarry = 0;
  for (int i = t; i < nbuck; i += 256) lcnt[i] = 0;
  __syncthreads();
  for (int c0 = 0; c0 < nbuck; c0 += 256) {
    int idx = c0 + t;
    int v = (idx < nbuck) ? bcnt[idx] : 0;
    stmp[t] = v;
    __syncthreads();
    for (int off = 1; off < 256; off <<= 1) {
      int u = (t >= off) ? stmp[t - off] : 0;
      __syncthreads();
      stmp[t] += u;
      __syncthreads();
    }
    int excl = stmp[t] - v + scarry;
    if (idx < nbuck) sbase[idx] = excl;
    __syncthreads();
    if (t == 255) scarry += stmp[255];
    __syncthreads();
  }
  // count this tile's edges per bucket
  for (int i = t; i < tn; i += 256)
    atomicAdd(&lcnt[dst[tile0 + i] >> BUCKET_SHIFT], 1);
  __syncthreads();
  // reserve global ranges (bcur is zero-based offset from sbase)
  for (int i = t; i < nbuck; i += 256) {
    int c = lcnt[i];
    gb[i] = c ? sbase[i] + atomicAdd(&bcur[i], c) : 0;
  }
  __syncthreads();
  for (int i = t; i < nbuck; i += 256) lcnt[i] = 0;
  __syncthreads();
  for (int i = t; i < tn; i += 256) {
    int d = dst[tile0 + i];
    int s = src[tile0 + i];
    int b = d >> BUCKET_SHIFT;
    int r = atomicAdd(&lcnt[b], 1);
    bucketed[gb[b] + r] = (s << 8) | (d & BUCKET_MASK);
  }
}

__global__ __launch_bounds__(256) void bucket_to_csr(const int* __restrict__ bucketed,
                                                     const int* __restrict__ bcnt,
                                                     int* __restrict__ rp,
                                                     float* __restrict__ dinv,
                                                     int* __restrict__ csr,
                                                     int n, int e, int nbuck) {
  int br = blockIdx.y;
  bucketed += (size_t)br * e;
  bcnt += (size_t)br * nbuck;
  rp += (size_t)br * (n + 1);
  dinv += (size_t)br * n;
  csr += (size_t)br * e;
  __shared__ int lcnt[256], lrp[256];
  __shared__ int sbb;
  int b = blockIdx.x, t = threadIdx.x;
  int n0 = b << BUCKET_SHIFT;
  // base = sum of bcnt[0..b)
  {
    int part = 0;
    for (int i = t; i < b; i += 256) part += bcnt[i];
    lrp[t] = part;
    __syncthreads();
    for (int s = 128; s > 0; s >>= 1) {
      if (t < s) lrp[t] += lrp[t + s];
      __syncthreads();
    }
    if (t == 0) sbb = lrp[0];
    __syncthreads();
  }
  int base = sbb;
  int cnt_e = bcnt[b];
  lcnt[t] = 0;
  __syncthreads();
  for (int i = t; i < cnt_e; i += 256)
    atomicAdd(&lcnt[bucketed[base + i] & BUCKET_MASK], 1);
  __syncthreads();
  int v = lcnt[t];
  lrp[t] = v;
  __syncthreads();
  for (int off = 1; off < 256; off <<= 1) {
    int u = (t >= off) ? lrp[t - off] : 0;
    __syncthreads();
    lrp[t] += u;
    __syncthreads();
  }
  int excl = lrp[t] - v;
  int node = n0 + t;
  if (node < n) {
    rp[node] = base + excl;
    dinv[node] = rsqrtf((float)v + 1.0f);   // +1 self loop
  }
  if (b == nbuck - 1 && t == 0) rp[n] = e;
  lrp[t] = excl;
  lcnt[t] = 0;
  __syncthreads();
  for (int i = t; i < cnt_e; i += 256) {
    int ed = bucketed[base + i];
    int li = ed & BUCKET_MASK;
    int pos = atomicAdd(&lcnt[li], 1);
    csr[base + lrp[li] + pos] = (int)(((unsigned)ed) >> 8);
  }
}

// ---------------- prep: xs scaling + graph boundaries (fused) -------------------
__global__ void prep(const float* __restrict__ x0, const float* __restrict__ x1,
                     const int* __restrict__ batch0, const int* __restrict__ batch1,
                     const float* __restrict__ dinv, float4* __restrict__ xs,
                     int* __restrict__ gstart, int n, int g) {
  int br = blockIdx.y;
  const float* x = br ? x1 : x0;
  const int* batch = br ? batch1 : batch0;
  dinv += (size_t)br * n;
  xs += (size_t)br * n;
  gstart += (size_t)br * (g + 1);
  int i = blockIdx.x * blockDim.x + threadIdx.x;
  if (i >= n) return;
  float d = dinv[i];
  xs[i] = make_float4(x[3 * (size_t)i] * d, x[3 * (size_t)i + 1] * d,
                      x[3 * (size_t)i + 2] * d, d);
  int b = batch[i];
  int bp = (i == 0) ? -1 : batch[i - 1];
  for (int k = bp + 1; k <= b; ++k) gstart[k] = i;
  if (i == n - 1)
    for (int k = b + 1; k <= g; ++k) gstart[k] = n;
}

// ---------------- layer-1 aggregation + block moments (8-deep pipeline) ---------
__global__ __launch_bounds__(256) void agg_f3(const float4* __restrict__ xs,
                                              const int* __restrict__ rp,
                                              const int* __restrict__ csr,
                                              const float* __restrict__ dinv,
                                              float4* __restrict__ out,
                                              float* __restrict__ mpart, int n, int e, int nb3) {
  int br = blockIdx.y;
  xs += (size_t)br * n;
  rp += (size_t)br * (n + 1);
  csr += (size_t)br * e;
  dinv += (size_t)br * n;
  out += (size_t)br * n;
  mpart += (size_t)br * nb3 * 9;
  int i = blockIdx.x * blockDim.x + threadIdx.x;
  int t = threadIdx.x;
  float a0 = 0.f, a1 = 0.f, a2 = 0.f;
  if (i < n) {
    float4 self = xs[i];
    a0 = self.x; a1 = self.y; a2 = self.z;
    int e0 = rp[i], e1 = rp[i + 1];
    int ee = e0;
    for (; ee + 8 <= e1; ee += 8) {
      int s0 = csr[ee],     s1 = csr[ee + 1], s2 = csr[ee + 2], s3 = csr[ee + 3];
      int s4 = csr[ee + 4], s5 = csr[ee + 5], s6 = csr[ee + 6], s7 = csr[ee + 7];
      float4 v0 = xs[s0], v1 = xs[s1], v2 = xs[s2], v3 = xs[s3];
      float4 v4 = xs[s4], v5 = xs[s5], v6 = xs[s6], v7 = xs[s7];
      a0 += ((v0.x + v1.x) + (v2.x + v3.x)) + ((v4.x + v5.x) + (v6.x + v7.x));
      a1 += ((v0.y + v1.y) + (v2.y + v3.y)) + ((v4.y + v5.y) + (v6.y + v7.y));
      a2 += ((v0.z + v1.z) + (v2.z + v3.z)) + ((v4.z + v5.z) + (v6.z + v7.z));
    }
    for (; ee + 4 <= e1; ee += 4) {
      int s0 = csr[ee], s1 = csr[ee + 1], s2 = csr[ee + 2], s3 = csr[ee + 3];
      float4 v0 = xs[s0], v1 = xs[s1], v2 = xs[s2], v3 = xs[s3];
      a0 += (v0.x + v1.x) + (v2.x + v3.x);
      a1 += (v0.y + v1.y) + (v2.y + v3.y);
      a2 += (v0.z + v1.z) + (v2.z + v3.z);
    }
    for (; ee < e1; ++ee) {
      float4 v = xs[csr[ee]];
      a0 += v.x; a1 += v.y; a2 += v.z;
    }
    float d = dinv[i];
    a0 *= d; a1 *= d; a2 *= d;
    out[i] = make_float4(a0, a1, a2, 0.f);
  }
  float loc[9] = {a0, a1, a2, a0 * a0, a0 * a1, a0 * a2, a1 * a1, a1 * a2, a2 * a2};
  __shared__ float red[256];
  for (int q = 0; q < 9; ++q) {
    red[t] = loc[q];
    __syncthreads();
    for (int s = 128; s > 0; s >>= 1) {
      if (t < s) red[t] += red[t + s];
      __syncthreads();
    }
    if (t == 0) mpart[blockIdx.x * 9 + q] = red[0];
    __syncthreads();
  }
}

// analytic BN1: fold BN scale directly into W1 -> W1s = (w*sc, be - mu0*sc)
__global__ void bnprep1(const float* __restrict__ mpart, int nblk,
                        const float* __restrict__ W1, const float* __restrict__ b1,
                        const float* __restrict__ g1, const float* __restrict__ be1,
                        float invn, float4* __restrict__ W1s) {
  int br = blockIdx.y;
  mpart += (size_t)br * nblk * 9;
  W1s += (size_t)br * 128;
  __shared__ float red[256];
  __shared__ float sm[9];
  int t = threadIdx.x;
  float loc[9] = {0.f, 0.f, 0.f, 0.f, 0.f, 0.f, 0.f, 0.f, 0.f};
  for (int i = t; i < nblk; i += 256)
#pragma unroll
    for (int q = 0; q < 9; ++q) loc[q] += mpart[i * 9 + q];
  for (int q = 0; q < 9; ++q) {
    red[t] = loc[q];
    __syncthreads();
    for (int s = 128; s > 0; s >>= 1) {
      if (t < s) red[t] += red[t + s];
      __syncthreads();
    }
    if (t == 0) sm[q] = red[0] * invn;
    __syncthreads();
  }
  if (t < 128) {
    float w0 = W1[t], w1 = W1[128 + t], w2 = W1[256 + t];
    float mu0 = sm[0] * w0 + sm[1] * w1 + sm[2] * w2;
    float q2 = w0 * w0 * sm[3] + w1 * w1 * sm[6] + w2 * w2 * sm[8]
             + 2.f * (w0 * w1 * sm[4] + w0 * w2 * sm[5] + w1 * w2 * sm[7]);
    float var = q2 - mu0 * mu0;
    float sc = rsqrtf(fmaxf(var, 0.f) + 1e-5f) * g1[t];
    W1s[t] = make_float4(w0 * sc, w1 * sc, w2 * sc, be1[t] - mu0 * sc);
  }
}

// ------- W split to MFMA-fragment-major layout (both weights in one launch) -----
__global__ void wsplit2(const float* __restrict__ W2, const float* __restrict__ W3,
                        unsigned short* __restrict__ Wf2, unsigned short* __restrict__ Wf3) {
  const float* W = blockIdx.y ? W3 : W2;
  unsigned short* Wf = blockIdx.y ? Wf3 : Wf2;
  int i = blockIdx.x * 256 + threadIdx.x;   // 16384 = 128x128
  if (i >= 128 * 128) return;
  int k = i >> 7, f = i & 127;
  float w = W[i];                            // W[k][f]
  unsigned short hi = f2bf(w);
  float hif = __uint_as_float((unsigned)hi << 16);
  unsigned short lo = f2bf(w - hif);
  int NT = f >> 4, l15 = f & 15, ks = k >> 5, lg = (k >> 3) & 3, j = k & 7;
  int lane = lg * 16 + l15;
  size_t base = ((size_t)(NT * 4 + ks) * 64 + lane) * 8 + j;
  Wf[base] = hi;
  Wf[16384 + base] = lo;
}

// ------ MFMA GEMM (swapped operands)
// MODE 1: BN+ReLU applied to bf16 A on load (layer 3)
// MODE 2: A computed on-the-fly from ag0 via fused lin1+BN+ReLU (layer 2)
template <int MODE>
__global__ __launch_bounds__(256) void gemm_mfma_t(const unsigned short* __restrict__ Abf,
                                                   const float4* __restrict__ ag0,
                                                   const float4* __restrict__ W1s,
                                                   const unsigned short* __restrict__ Wf,
                                                   const float* __restrict__ dinv,
                                                   const float2* __restrict__ prm,
                                                   unsigned short* __restrict__ C, int n) {
  int br = blockIdx.y;
  if (MODE == 1) { Abf += (size_t)br * n * 128; prm += (size_t)br * 128; }
  if (MODE == 2) { ag0 += (size_t)br * n; W1s += (size_t)br * 128; }
  dinv += (size_t)br * n;
  C += (size_t)br * n * 128;
  const int t = threadIdx.x;
  const int wave = t >> 6, lane = t & 63;
  const int l15 = lane & 15, lg = lane >> 4;
  const int row0 = blockIdx.x * 128 + wave * 32;
  const int n0 = row0 + l15, n1 = row0 + 16 + l15;
  const bf16x8* wfr = (const bf16x8*)Wf;       // hi frags [0..2047], lo at +2048
  float4 a0v = make_float4(0.f, 0.f, 0.f, 0.f), a1v = a0v;
  if (MODE == 2) {
    if (n0 < n) a0v = ag0[n0];
    if (n1 < n) a1v = ag0[n1];
  }
  f32x4 acc[8][2] = {};
#pragma unroll
  for (int ks = 0; ks < 4; ++ks) {
    int k0 = ks * 32 + lg * 8;
    bf16x8 nf0 = {}, nf1 = {};
    if (MODE == 1) {
      if (n0 < n) nf0 = *(const bf16x8*)&Abf[(size_t)n0 * 128 + k0];
      if (n1 < n) nf1 = *(const bf16x8*)&Abf[(size_t)n1 * 128 + k0];
      float4 pa = *(const float4*)&prm[k0];
      float4 pb = *(const float4*)&prm[k0 + 2];
      float4 pc = *(const float4*)&prm[k0 + 4];
      float4 pd = *(const float4*)&prm[k0 + 6];
      float scv[8] = {pa.x, pa.z, pb.x, pb.z, pc.x, pc.z, pd.x, pd.z};
      float ofv[8] = {pa.y, pa.w, pb.y, pb.w, pc.y, pc.w, pd.y, pd.w};
#pragma unroll
      for (int j = 0; j < 8; ++j) {
        float x0 = fmaxf(bf2f((unsigned short)nf0[j]) * scv[j] + ofv[j], 0.f);
        float x1 = fmaxf(bf2f((unsigned short)nf1[j]) * scv[j] + ofv[j], 0.f);
        nf0[j] = (short)f2bf(x0);
        nf1[j] = (short)f2bf(x1);
      }
    } else {   // MODE == 2: fused lin1+BN+ReLU from ag0 (scale pre-folded into W1s)
#pragma unroll
      for (int j = 0; j < 8; ++j) {
        int f = k0 + j;
        float4 wv = W1s[f];
        float x0 = a0v.x * wv.x + a0v.y * wv.y + a0v.z * wv.z + wv.w;
        float x1 = a1v.x * wv.x + a1v.y * wv.y + a1v.z * wv.z + wv.w;
        nf0[j] = (short)f2bf(fmaxf(x0, 0.f));
        nf1[j] = (short)f2bf(fmaxf(x1, 0.f));
      }
    }
#pragma unroll
    for (int NT = 0; NT < 8; ++NT) {
      bf16x8 wh = wfr[(NT * 4 + ks) * 64 + lane];
      bf16x8 wl = wfr[2048 + (NT * 4 + ks) * 64 + lane];
      acc[NT][0] = __builtin_amdgcn_mfma_f32_16x16x32_bf16(wh, nf0, acc[NT][0], 0, 0, 0);
      acc[NT][0] = __builtin_amdgcn_mfma_f32_16x16x32_bf16(wl, nf0, acc[NT][0], 0, 0, 0);
      acc[NT][1] = __builtin_amdgcn_mfma_f32_16x16x32_bf16(wh, nf1, acc[NT][1], 0, 0, 0);
      acc[NT][1] = __builtin_amdgcn_mfma_f32_16x16x32_bf16(wl, nf1, acc[NT][1], 0, 0, 0);
    }
  }
  float sc0 = (n0 < n) ? dinv[n0] : 0.f;
  float sc1 = (n1 < n) ? dinv[n1] : 0.f;
#pragma unroll
  for (int ng = 0; ng < 2; ++ng) {
    int node = (ng == 0) ? n0 : n1;
    float sc = (ng == 0) ? sc0 : sc1;
    if (node < n) {
#pragma unroll
      for (int NT = 0; NT < 8; ++NT) {
        ushort4 o;
        o.x = f2bf(acc[NT][ng][0] * sc);
        o.y = f2bf(acc[NT][ng][1] * sc);
        o.z = f2bf(acc[NT][ng][2] * sc);
        o.w = f2bf(acc[NT][ng][3] * sc);
        *(ushort4*)&C[(size_t)node * 128 + NT * 16 + lg * 4] = o;
      }
    }
  }
}

// ------- layer-2 aggregation: bf16 out + fused per-block BN partial stats -------
__global__ __launch_bounds__(256) void agg128_l2(const unsigned short* __restrict__ h,
                                                 const int* __restrict__ rp,
                                                 const int* __restrict__ csr,
                                                 const float* __restrict__ dinv,
                                                 const float* __restrict__ bias,
                                                 unsigned short* __restrict__ outb,
                                                 float* __restrict__ mpart, int n, int e,
                                                 int nagg) {
  int br = blockIdx.y;
  h += (size_t)br * n * 128;
  rp += (size_t)br * (n + 1);
  csr += (size_t)br * e;
  dinv += (size_t)br * n;
  outb += (size_t)br * n * 128;
  mpart += (size_t)br * nagg * 256;
  int t = threadIdx.x;
  int node = blockIdx.x * 16 + (t >> 4);
  int lane = t & 15;
  bool valid = node < n;
  const uint4* hp = (const uint4*)h;
  float acc[8] = {0.f};
  if (valid) {
    acc8(acc, hp[(size_t)node * 16 + lane]);
    int e0 = rp[node], e1 = rp[node + 1];
    int ee = e0;
    for (; ee + 8 <= e1; ee += 8) {
      int s0 = csr[ee],     s1 = csr[ee + 1], s2 = csr[ee + 2], s3 = csr[ee + 3];
      int s4 = csr[ee + 4], s5 = csr[ee + 5], s6 = csr[ee + 6], s7 = csr[ee + 7];
      uint4 v0 = hp[(size_t)s0 * 16 + lane];
      uint4 v1 = hp[(size_t)s1 * 16 + lane];
      uint4 v2 = hp[(size_t)s2 * 16 + lane];
      uint4 v3 = hp[(size_t)s3 * 16 + lane];
      uint4 v4 = hp[(size_t)s4 * 16 + lane];
      uint4 v5 = hp[(size_t)s5 * 16 + lane];
      uint4 v6 = hp[(size_t)s6 * 16 + lane];
      uint4 v7 = hp[(size_t)s7 * 16 + lane];
      acc8(acc, v0); acc8(acc, v1); acc8(acc, v2); acc8(acc, v3);
      acc8(acc, v4); acc8(acc, v5); acc8(acc, v6); acc8(acc, v7);
    }
    for (; ee + 4 <= e1; ee += 4) {
      int s0 = csr[ee], s1 = csr[ee + 1], s2 = csr[ee + 2], s3 = csr[ee + 3];
      uint4 v0 = hp[(size_t)s0 * 16 + lane];
      uint4 v1 = hp[(size_t)s1 * 16 + lane];
      uint4 v2 = hp[(size_t)s2 * 16 + lane];
      uint4 v3 = hp[(size_t)s3 * 16 + lane];
      acc8(acc, v0); acc8(acc, v1); acc8(acc, v2); acc8(acc, v3);
    }
    for (; ee < e1; ++ee) acc8(acc, hp[(size_t)csr[ee] * 16 + lane]);
  }
  float v[8], sq[8];
  if (valid) {
    float dd = dinv[node];
    float4 bb0 = *(const float4*)&bias[lane * 8];
    float4 bb1 = *(const float4*)&bias[lane * 8 + 4];
    v[0] = acc[0] * dd + bb0.x; v[1] = acc[1] * dd + bb0.y;
    v[2] = acc[2] * dd + bb0.z; v[3] = acc[3] * dd + bb0.w;
    v[4] = acc[4] * dd + bb1.x; v[5] = acc[5] * dd + bb1.y;
    v[6] = acc[6] * dd + bb1.z; v[7] = acc[7] * dd + bb1.w;
    uint4 o;
    o.x = pack2(v[0], v[1]); o.y = pack2(v[2], v[3]);
    o.z = pack2(v[4], v[5]); o.w = pack2(v[6], v[7]);
    *(uint4*)&outb[(size_t)node * 128 + lane * 8] = o;
  } else {
#pragma unroll
    for (int j = 0; j < 8; ++j) v[j] = 0.f;
  }
#pragma unroll
  for (int j = 0; j < 8; ++j) sq[j] = v[j] * v[j];
#pragma unroll
  for (int j = 0; j < 8; ++j) {
    v[j] += __shfl_xor(v[j], 16);  v[j] += __shfl_xor(v[j], 32);
    sq[j] += __shfl_xor(sq[j], 16); sq[j] += __shfl_xor(sq[j], 32);
  }
  __shared__ float sred[4][16][16];
  int wave = t >> 6, wl = t & 63;
  if (wl < 16) {
#pragma unroll
    for (int j = 0; j < 8; ++j) {
      sred[wave][wl][j] = v[j];
      sred[wave][wl][8 + j] = sq[j];
    }
  }
  __syncthreads();
  {
    int f = t & 127;
    int j = (f & 7) + ((t >> 7) << 3);   // 0-7 sum, 8-15 sumsq
    float s = sred[0][f >> 3][j] + sred[1][f >> 3][j]
            + sred[2][f >> 3][j] + sred[3][f >> 3][j];
    mpart[(size_t)blockIdx.x * 256 + t] = s;
  }
}

// stage-1 reduce of BN partials (32 blocks)
__global__ __launch_bounds__(256) void bnred1(const float* __restrict__ mpart, int nblk,
                                              float* __restrict__ spart) {
  int br = blockIdx.y;
  mpart += (size_t)br * nblk * 256;
  spart += (size_t)br * 32 * 256;
  int t = threadIdx.x, b = blockIdx.x;
  float loc = 0.f;
  for (int i = b; i < nblk; i += 32) loc += mpart[(size_t)i * 256 + t];
  spart[b * 256 + t] = loc;
}

// stage-2: fold partials, compute per-feature (scale, offset)
__global__ void bnprep2(const float* __restrict__ spart,
                        const float* __restrict__ gam, const float* __restrict__ bet,
                        float invn, float2* __restrict__ prm) {
  int br = blockIdx.y;
  spart += (size_t)br * 32 * 256;
  prm += (size_t)br * 128;
  int t = threadIdx.x;
  float loc = 0.f;
  for (int i = 0; i < 32; ++i) loc += spart[i * 256 + t];
  __shared__ float sm[256];
  sm[t] = loc;
  __syncthreads();
  if (t < 128) {
    float mu = sm[t] * invn;
    float var = sm[128 + t] * invn - mu * mu;
    float sc = rsqrtf(fmaxf(var, 0.f) + 1e-5f) * gam[t];
    prm[t] = make_float2(sc, bet[t] - mu * sc);
  }
}

// ------- layer-3 aggregation with fused mean-pool accumulation ------------------
__global__ __launch_bounds__(256) void agg128_l3_pool(const unsigned short* __restrict__ h,
                                                      const int* __restrict__ rp,
                                                      const int* __restrict__ csr,
                                                      const float* __restrict__ dinv,
                                                      const float* __restrict__ bias,
                                                      const int* __restrict__ batch0,
                                                      const int* __restrict__ batch1,
                                                      float* __restrict__ pooled,
                                                      int n, int e, int g) {
  int br = blockIdx.y;
  h += (size_t)br * n * 128;
  rp += (size_t)br * (n + 1);
  csr += (size_t)br * e;
  dinv += (size_t)br * n;
  const int* batch = br ? batch1 : batch0;
  pooled += (size_t)br * g * 128;
  int t = threadIdx.x;
  int node = blockIdx.x * 16 + (t >> 4);
  int lane = t & 15;
  bool valid = node < n;
  const uint4* hp = (const uint4*)h;
  float acc[8] = {0.f};
  if (valid) {
    acc8(acc, hp[(size_t)node * 16 + lane]);
    int e0 = rp[node], e1 = rp[node + 1];
    int ee = e0;
    for (; ee + 8 <= e1; ee += 8) {
      int s0 = csr[ee],     s1 = csr[ee + 1], s2 = csr[ee + 2], s3 = csr[ee + 3];
      int s4 = csr[ee + 4], s5 = csr[ee + 5], s6 = csr[ee + 6], s7 = csr[ee + 7];
      uint4 v0 = hp[(size_t)s0 * 16 + lane];
      uint4 v1 = hp[(size_t)s1 * 16 + lane];
      uint4 v2 = hp[(size_t)s2 * 16 + lane];
      uint4 v3 = hp[(size_t)s3 * 16 + lane];
      uint4 v4 = hp[(size_t)s4 * 16 + lane];
      uint4 v5 = hp[(size_t)s5 * 16 + lane];
      uint4 v6 = hp[(size_t)s6 * 16 + lane];
      uint4 v7 = hp[(size_t)s7 * 16 + lane];
      acc8(acc, v0); acc8(acc, v1); acc8(acc, v2); acc8(acc, v3);
      acc8(acc, v4); acc8(acc, v5); acc8(acc, v6); acc8(acc, v7);
    }
    for (; ee + 4 <= e1; ee += 4) {
      int s0 = csr[ee], s1 = csr[ee + 1], s2 = csr[ee + 2], s3 = csr[ee + 3];
      uint4 v0 = hp[(size_t)s0 * 16 + lane];
      uint4 v1 = hp[(size_t)s1 * 16 + lane];
      uint4 v2 = hp[(size_t)s2 * 16 + lane];
      uint4 v3 = hp[(size_t)s3 * 16 + lane];
      acc8(acc, v0); acc8(acc, v1); acc8(acc, v2); acc8(acc, v3);
    }
    for (; ee < e1; ++ee) acc8(acc, hp[(size_t)csr[ee] * 16 + lane]);
  }
  __shared__ float lds[16][128];
  __shared__ int lgid[16];
  int ng = t >> 4;
  if (valid) {
    float dd = dinv[node];
    float4 bb0 = *(const float4*)&bias[lane * 8];
    float4 bb1 = *(const float4*)&bias[lane * 8 + 4];
    float w0 = bf2f(f2bf(acc[0] * dd + bb0.x));
    float w1 = bf2f(f2bf(acc[1] * dd + bb0.y));
    float w2 = bf2f(f2bf(acc[2] * dd + bb0.z));
    float w3 = bf2f(f2bf(acc[3] * dd + bb0.w));
    float w4 = bf2f(f2bf(acc[4] * dd + bb1.x));
    float w5 = bf2f(f2bf(acc[5] * dd + bb1.y));
    float w6 = bf2f(f2bf(acc[6] * dd + bb1.z));
    float w7 = bf2f(f2bf(acc[7] * dd + bb1.w));
    lds[ng][lane * 8 + 0] = w0; lds[ng][lane * 8 + 1] = w1;
    lds[ng][lane * 8 + 2] = w2; lds[ng][lane * 8 + 3] = w3;
    lds[ng][lane * 8 + 4] = w4; lds[ng][lane * 8 + 5] = w5;
    lds[ng][lane * 8 + 6] = w6; lds[ng][lane * 8 + 7] = w7;
    if (lane == 0) lgid[ng] = batch[node];
  } else {
#pragma unroll
    for (int j = 0; j < 8; ++j) lds[ng][lane * 8 + j] = 0.f;
    if (lane == 0) lgid[ng] = -1;
  }
  __syncthreads();
  {
    int f = t & 127, half = t >> 7;
    int lo = half * 8, hi = lo + 8;
    float run = 0.f;
    int cur = lgid[lo];
    for (int k = lo; k < hi; ++k) {
      int gg = lgid[k];
      if (gg != cur) {
        if (cur >= 0 && run != 0.f) atomicAdd(&pooled[cur * 128 + f], run);
        run = 0.f;
        cur = gg;
      }
      run += lds[k][f];
    }
    if (cur >= 0 && run != 0.f) atomicAdd(&pooled[cur * 128 + f], run);
  }
}

// ---------------- MLP head + L2 normalize ----------------
__global__ void mlp_kernel(const float* __restrict__ pooled, const int* __restrict__ gstart,
                           const float* __restrict__ Wp1, const float* __restrict__ bp1,
                           const float* __restrict__ Wp2, const float* __restrict__ bp2,
                           float* __restrict__ out, int g) {
  int br = blockIdx.y;
  pooled += (size_t)br * g * 128;
  gstart += (size_t)br * (g + 1);
  out += (size_t)br * g * 512;
  int gg = blockIdx.x, t = threadIdx.x;
  __shared__ float pv[128], hid[128], ov[512], red[256];
  if (t < 128) {
    float cntf = (float)(gstart[gg + 1] - gstart[gg]);
    pv[t] = pooled[gg * 128 + t] / fmaxf(cntf, 1.0f);
  }
  __syncthreads();
  if (t < 128) {
    float a = bp1[t];
    for (int k = 0; k < 128; ++k) a += pv[k] * Wp1[k * 128 + t];
    hid[t] = fmaxf(a, 0.0f);
  }
  __syncthreads();
  for (int o = t; o < 512; o += 256) {
    float a = bp2[o];
    for (int k = 0; k < 128; ++k) a += hid[k] * Wp2[k * 512 + o];
    ov[o] = a;
  }
  __syncthreads();
  red[t] = ov[t] * ov[t] + ov[t + 256] * ov[t + 256];
  __syncthreads();
  for (int sdt = 128; sdt > 0; sdt >>= 1) {
    if (t < sdt) red[t] += red[t + sdt];
    __syncthreads();
  }
  float inv = 1.0f / fmaxf(sqrtf(red[0]), 1e-12f);
  for (int o = t; o < 512; o += 256) out[(size_t)gg * 512 + o] = ov[o] * inv;
}

// ---------------- host orchestration ----------------
extern "C" void kernel_launch(void* const* d_in, const int* in_sizes, int n_in,
                              void* d_out, int out_size, void* d_ws, size_t ws_size,
                              hipStream_t stream) {
  const int N = in_sizes[0] / 3;
  const int E = in_sizes[1] / 2;
  const int G = out_size / (2 * 512);
  const int NBUCK = (N + BUCKET_MASK) >> BUCKET_SHIFT;
  const int NB3 = (N + 255) / 256;
  const int NAGG = (N + 15) / 16;

  char* w = (char*)d_ws;
  auto alloc = [&](size_t bytes) -> void* {
    void* p = (void*)w;
    w += (bytes + 255) & ~(size_t)255;
    return p;
  };
  // zero-block: bcnt | bcur | pooled, zeroed in one launch
  int*            bcnt     = (int*)alloc(2 * (size_t)NBUCK * 4);
  int*            bcur     = (int*)alloc(2 * (size_t)NBUCK * 4);
  float*          pooled   = (float*)alloc(2 * (size_t)G * 128 * 4);
  char*           zend     = w;
  unsigned short* Abf      = (unsigned short*)alloc(2 * (size_t)N * 128 * 2);
  unsigned short* Bh       = (unsigned short*)alloc(2 * (size_t)N * 128 * 2);
  float*          dinv     = (float*)alloc(2 * (size_t)N * 4);
  float4*         xs       = (float4*)alloc(2 * (size_t)N * 16);
  float4*         ag0      = (float4*)alloc(2 * (size_t)N * 16);
  int*            rp       = (int*)alloc(2 * (size_t)(N + 1) * 4);
  int*            csr      = (int*)alloc(2 * (size_t)E * 4);
  int*            bucketed = (int*)alloc(2 * (size_t)E * 4);
  int*            gstart   = (int*)alloc(2 * (size_t)(G + 1) * 4);
  unsigned short* Wf2      = (unsigned short*)alloc(2 * 128 * 128 * 2);
  unsigned short* Wf3      = (unsigned short*)alloc(2 * 128 * 128 * 2);
  float*          mpart    = (float*)alloc(2 * (size_t)NB3 * 9 * 4);
  float*          mpart2   = (float*)alloc(2 * (size_t)NAGG * 256 * 4);
  float*          spart    = (float*)alloc(2 * (size_t)32 * 256 * 4);
  float4*         W1s      = (float4*)alloc(2 * 128 * 16);
  float2*         prm2     = (float2*)alloc(2 * 128 * 8);

  const float* x0    = (const float*)d_in[0];
  const int*   ei0   = (const int*)d_in[1];
  const int*   bat0  = (const int*)d_in[2];
  const float* x1    = (const float*)d_in[3];
  const int*   ei1   = (const int*)d_in[4];
  const int*   bat1  = (const int*)d_in[5];
  const float* W1  = (const float*)d_in[6];
  const float* b1  = (const float*)d_in[7];
  const float* W2  = (const float*)d_in[8];
  const float* b2  = (const float*)d_in[9];
  const float* W3  = (const float*)d_in[10];
  const float* b3  = (const float*)d_in[11];
  const float* g1  = (const float*)d_in[12];
  const float* be1 = (const float*)d_in[13];
  const float* g2  = (const float*)d_in[14];
  const float* be2 = (const float*)d_in[15];
  const float* Wp1 = (const float*)d_in[16];
  const float* bp1 = (const float*)d_in[17];
  const float* Wp2 = (const float*)d_in[18];
  const float* bp2 = (const float*)d_in[19];

  const int* src0 = ei0;
  const int* dst0 = ei0 + E;
  const int* src1 = ei1;
  const int* dst1 = ei1 + E;
  float* outp = (float*)d_out;

  const int TB = 256;
  const int NTILE = (E + TILE - 1) / TILE;
  const float invn = 1.0f / (float)N;
  const int zcnt = (int)((zend - (char*)bcnt) / 4);

  // one upfront zero of bcnt|bcur|pooled
  zero_u32<<<(zcnt + TB - 1) / TB, TB, 0, stream>>>((unsigned*)bcnt, zcnt);
  wsplit2<<<dim3(64, 2), TB, 0, stream>>>(W2, W3, Wf2, Wf3);

  // CSR build (both branches batched, bucket scan fused into consumers)
  bucket_count<<<dim3(256, 2), TB, 0, stream>>>(dst0, dst1, bcnt, E, NBUCK);
  bucket_scatter<<<dim3(NTILE, 2), TB, 0, stream>>>(src0, dst0, src1, dst1, bcnt, bcur,
                                                    bucketed, E, NBUCK);
  bucket_to_csr<<<dim3(NBUCK, 2), TB, 0, stream>>>(bucketed, bcnt, rp, dinv, csr, N, E, NBUCK);

  // prep: xs scaling + graph boundaries
  prep<<<dim3((N + TB - 1) / TB, 2), TB, 0, stream>>>(x0, x1, bat0, bat1, dinv, xs, gstart, N, G);

  // layer 1: aggregate + moments, analytic BN folded into W1
  agg_f3<<<dim3(NB3, 2), TB, 0, stream>>>(xs, rp, csr, dinv, ag0, mpart, N, E, NB3);
  bnprep1<<<dim3(1, 2), TB, 0, stream>>>(mpart, NB3, W1, b1, g1, be1, invn, W1s);

  // layer 2: gemm (fused lin1+BN1+ReLU from ag0) -> agg (bf16 out + BN stats)
  gemm_mfma_t<2><<<dim3((N + 127) / 128, 2), TB, 0, stream>>>(nullptr, ag0, W1s, Wf2, dinv,
                                                              nullptr, Bh, N);
  agg128_l2<<<dim3(NAGG, 2), TB, 0, stream>>>(Bh, rp, csr, dinv, b2, Abf, mpart2, N, E, NAGG);
  bnred1<<<dim3(32, 2), TB, 0, stream>>>(mpart2, NAGG, spart);
  bnprep2<<<dim3(1, 2), TB, 0, stream>>>(spart, g2, be2, invn, prm2);

  // layer 3: gemm with BN2+ReLU fused on load -> agg with fused mean-pool
  gemm_mfma_t<1><<<dim3((N + 127) / 128, 2), TB, 0, stream>>>(Abf, nullptr, nullptr, Wf3, dinv,
                                                              prm2, Bh, N);
  agg128_l3_pool<<<dim3(NAGG, 2), TB, 0, stream>>>(Bh, rp, csr, dinv, b3, bat0, bat1, pooled,
                                                   N, E, G);

  // head
  mlp_kernel<<<dim3(G, 2), TB, 0, stream>>>(pooled, gstart, Wp1, bp1, Wp2, bp2, outp, G);
}

// Round 12
// 743.679 us; speedup vs baseline: 1.0391x; 1.0391x over previous
//
#include <hip/hip_runtime.h>
#include <math.h>

#define BUCKET_SHIFT 8            // 256 nodes per bucket
#define BUCKET_MASK 255
#define MAXBUCK 640               // supports N <= 163840
#define TILE 8192

typedef __attribute__((ext_vector_type(8))) short bf16x8;
typedef __attribute__((ext_vector_type(4))) float f32x4;

__device__ inline float bf_lo(unsigned u) { return __uint_as_float(u << 16); }
__device__ inline float bf_hi(unsigned u) { return __uint_as_float(u & 0xffff0000u); }
__device__ inline float bf2f(unsigned short s) { return __uint_as_float((unsigned)s << 16); }
__device__ inline unsigned short f2bf(float f) {   // round-to-nearest-even
  unsigned u = __float_as_uint(f);
  return (unsigned short)((u + 0x7fffu + ((u >> 16) & 1u)) >> 16);
}
__device__ inline void acc8(float* a, uint4 v) {
  a[0] += bf_lo(v.x); a[1] += bf_hi(v.x);
  a[2] += bf_lo(v.y); a[3] += bf_hi(v.y);
  a[4] += bf_lo(v.z); a[5] += bf_hi(v.z);
  a[6] += bf_lo(v.w); a[7] += bf_hi(v.w);
}
__device__ inline unsigned pack2(float a, float b) {
  return (unsigned)f2bf(a) | ((unsigned)f2bf(b) << 16);
}

// ---------------- utility ----------------
__global__ void zero_u32(unsigned int* __restrict__ p, int n) {
  int i = blockIdx.x * blockDim.x + threadIdx.x;
  if (i < n) p[i] = 0u;
}

// ---------------- bucketed CSR build (branch-batched via blockIdx.y) ------------
__global__ __launch_bounds__(256) void bucket_count(const int* __restrict__ dst0,
                                                    const int* __restrict__ dst1,
                                                    int* __restrict__ bcnt, int e, int nbuck) {
  int br = blockIdx.y;
  const int* dst = br ? dst1 : dst0;
  bcnt += (size_t)br * nbuck;
  __shared__ int lc[MAXBUCK];
  for (int i = threadIdx.x; i < nbuck; i += 256) lc[i] = 0;
  __syncthreads();
  for (int i = blockIdx.x * blockDim.x + threadIdx.x; i < e; i += gridDim.x * blockDim.x)
    atomicAdd(&lc[dst[i] >> BUCKET_SHIFT], 1);
  __syncthreads();
  for (int i = threadIdx.x; i < nbuck; i += 256)
    if (lc[i]) atomicAdd(&bcnt[i], lc[i]);
}

__global__ __launch_bounds__(1024) void bucket_scan(const int* __restrict__ bcnt,
                                                    int* __restrict__ bbase,
                                                    int* __restrict__ bcur, int nbuck) {
  int br = blockIdx.y;
  bcnt += (size_t)br * nbuck;
  bbase += (size_t)br * (nbuck + 1);
  bcur += (size_t)br * nbuck;
  __shared__ int s[1024];
  int t = threadIdx.x;
  int v = (t < nbuck) ? bcnt[t] : 0;
  s[t] = v;
  __syncthreads();
  for (int off = 1; off < 1024; off <<= 1) {
    int u = (t >= off) ? s[t - off] : 0;
    __syncthreads();
    s[t] += u;
    __syncthreads();
  }
  int excl = s[t] - v;
  if (t < nbuck) {
    bbase[t] = excl;
    bcur[t] = excl;
  } else if (t == nbuck) {
    bbase[t] = excl;
  }
}

// rank-based scatter (order within a bucket is arbitrary)
__global__ __launch_bounds__(256) void bucket_scatter(const int* __restrict__ src0,
                                                      const int* __restrict__ dst0,
                                                      const int* __restrict__ src1,
                                                      const int* __restrict__ dst1,
                                                      int* __restrict__ bcur,
                                                      int* __restrict__ bucketed,
                                                      int e, int nbuck) {
  int br = blockIdx.y;
  const int* src = br ? src1 : src0;
  const int* dst = br ? dst1 : dst0;
  bcur += (size_t)br * nbuck;
  bucketed += (size_t)br * e;
  __shared__ int lcnt[MAXBUCK], gb[MAXBUCK];
  int t = threadIdx.x;
  int tile0 = blockIdx.x * TILE;
  int tn = min(TILE, e - tile0);
  for (int i = t; i < nbuck; i += 256) lcnt[i] = 0;
  __syncthreads();
  for (int i = t; i < tn; i += 256)
    atomicAdd(&lcnt[dst[tile0 + i] >> BUCKET_SHIFT], 1);
  __syncthreads();
  for (int i = t; i < nbuck; i += 256) {
    int c = lcnt[i];
    gb[i] = c ? atomicAdd(&bcur[i], c) : 0;
  }
  __syncthreads();
  for (int i = t; i < nbuck; i += 256) lcnt[i] = 0;
  __syncthreads();
  for (int i = t; i < tn; i += 256) {
    int d = dst[tile0 + i];
    int s = src[tile0 + i];
    int b = d >> BUCKET_SHIFT;
    int r = atomicAdd(&lcnt[b], 1);
    bucketed[gb[b] + r] = (s << 8) | (d & BUCKET_MASK);
  }
}

__global__ __launch_bounds__(256) void bucket_to_csr(const int* __restrict__ bucketed,
                                                     const int* __restrict__ bbase,
                                                     int* __restrict__ rp,
                                                     float* __restrict__ dinv,
                                                     int* __restrict__ csr,
                                                     int n, int e, int nbuck) {
  int br = blockIdx.y;
  bucketed += (size_t)br * e;
  bbase += (size_t)br * (nbuck + 1);
  rp += (size_t)br * (n + 1);
  dinv += (size_t)br * n;
  csr += (size_t)br * e;
  __shared__ int lcnt[256], lrp[256];
  int b = blockIdx.x, t = threadIdx.x;
  int n0 = b << BUCKET_SHIFT;
  int base = bbase[b];
  int cnt_e = bbase[b + 1] - base;
  lcnt[t] = 0;
  __syncthreads();
  for (int i = t; i < cnt_e; i += 256)
    atomicAdd(&lcnt[bucketed[base + i] & BUCKET_MASK], 1);
  __syncthreads();
  int v = lcnt[t];
  lrp[t] = v;
  __syncthreads();
  for (int off = 1; off < 256; off <<= 1) {
    int u = (t >= off) ? lrp[t - off] : 0;
    __syncthreads();
    lrp[t] += u;
    __syncthreads();
  }
  int excl = lrp[t] - v;
  int node = n0 + t;
  if (node < n) {
    rp[node] = base + excl;
    dinv[node] = rsqrtf((float)v + 1.0f);   // +1 self loop
  }
  if (b == nbuck - 1 && t == 0) rp[n] = e;
  lrp[t] = excl;
  lcnt[t] = 0;
  __syncthreads();
  for (int i = t; i < cnt_e; i += 256) {
    int ed = bucketed[base + i];
    int li = ed & BUCKET_MASK;
    int pos = atomicAdd(&lcnt[li], 1);
    csr[base + lrp[li] + pos] = (int)(((unsigned)ed) >> 8);
  }
}

// ---------------- graph boundaries from sorted batch (no atomics) ----------------
__global__ void graph_bounds(const int* __restrict__ batch0, const int* __restrict__ batch1,
                             int* __restrict__ gstart, int n, int g) {
  int br = blockIdx.y;
  const int* batch = br ? batch1 : batch0;
  gstart += (size_t)br * (g + 1);
  int i = blockIdx.x * blockDim.x + threadIdx.x;
  if (i >= n) return;
  int b = batch[i];
  int bp = (i == 0) ? -1 : batch[i - 1];
  for (int k = bp + 1; k <= b; ++k) gstart[k] = i;
  if (i == n - 1)
    for (int k = b + 1; k <= g; ++k) gstart[k] = n;
}

// ---------------- layer 1 ----------------
__global__ void xs_scale(const float* __restrict__ x0, const float* __restrict__ x1,
                         const float* __restrict__ dinv, float4* __restrict__ xs, int n) {
  int br = blockIdx.y;
  const float* x = br ? x1 : x0;
  dinv += (size_t)br * n;
  xs += (size_t)br * n;
  int i = blockIdx.x * blockDim.x + threadIdx.x;
  if (i >= n) return;
  float d = dinv[i];
  xs[i] = make_float4(x[3 * (size_t)i] * d, x[3 * (size_t)i + 1] * d,
                      x[3 * (size_t)i + 2] * d, d);
}

__global__ __launch_bounds__(256) void agg_f3(const float4* __restrict__ xs,
                                              const int* __restrict__ rp,
                                              const int* __restrict__ csr,
                                              const float* __restrict__ dinv,
                                              float4* __restrict__ out,
                                              float* __restrict__ mpart, int n, int e, int nb3) {
  int br = blockIdx.y;
  xs += (size_t)br * n;
  rp += (size_t)br * (n + 1);
  csr += (size_t)br * e;
  dinv += (size_t)br * n;
  out += (size_t)br * n;
  mpart += (size_t)br * nb3 * 9;
  int i = blockIdx.x * blockDim.x + threadIdx.x;
  int t = threadIdx.x;
  float a0 = 0.f, a1 = 0.f, a2 = 0.f;
  if (i < n) {
    float4 self = xs[i];
    a0 = self.x; a1 = self.y; a2 = self.z;
    int e0 = rp[i], e1 = rp[i + 1];
    int ee = e0;
    for (; ee + 4 <= e1; ee += 4) {
      int s0 = csr[ee], s1 = csr[ee + 1], s2 = csr[ee + 2], s3 = csr[ee + 3];
      float4 v0 = xs[s0], v1 = xs[s1], v2 = xs[s2], v3 = xs[s3];
      a0 += (v0.x + v1.x) + (v2.x + v3.x);
      a1 += (v0.y + v1.y) + (v2.y + v3.y);
      a2 += (v0.z + v1.z) + (v2.z + v3.z);
    }
    for (; ee < e1; ++ee) {
      float4 v = xs[csr[ee]];
      a0 += v.x; a1 += v.y; a2 += v.z;
    }
    float d = dinv[i];
    a0 *= d; a1 *= d; a2 *= d;
    out[i] = make_float4(a0, a1, a2, 0.f);
  }
  float loc[9] = {a0, a1, a2, a0 * a0, a0 * a1, a0 * a2, a1 * a1, a1 * a2, a2 * a2};
  __shared__ float red[256];
  for (int q = 0; q < 9; ++q) {
    red[t] = loc[q];
    __syncthreads();
    for (int s = 128; s > 0; s >>= 1) {
      if (t < s) red[t] += red[t + s];
      __syncthreads();
    }
    if (t == 0) mpart[blockIdx.x * 9 + q] = red[0];
    __syncthreads();
  }
}

__global__ void bnprep1(const float* __restrict__ mpart, int nblk,
                        const float* __restrict__ W1, const float* __restrict__ b1,
                        const float* __restrict__ g1, const float* __restrict__ be1,
                        float invn, float4* __restrict__ W1r, float2* __restrict__ prm) {
  int br = blockIdx.y;
  mpart += (size_t)br * nblk * 9;
  W1r += (size_t)br * 128;
  prm += (size_t)br * 128;
  __shared__ float red[256];
  __shared__ float sm[9];
  int t = threadIdx.x;
  float loc[9] = {0.f, 0.f, 0.f, 0.f, 0.f, 0.f, 0.f, 0.f, 0.f};
  for (int i = t; i < nblk; i += 256)
#pragma unroll
    for (int q = 0; q < 9; ++q) loc[q] += mpart[i * 9 + q];
  for (int q = 0; q < 9; ++q) {
    red[t] = loc[q];
    __syncthreads();
    for (int s = 128; s > 0; s >>= 1) {
      if (t < s) red[t] += red[t + s];
      __syncthreads();
    }
    if (t == 0) sm[q] = red[0] * invn;
    __syncthreads();
  }
  if (t < 128) {
    float w0 = W1[t], w1 = W1[128 + t], w2 = W1[256 + t];
    float mu0 = sm[0] * w0 + sm[1] * w1 + sm[2] * w2;
    float q2 = w0 * w0 * sm[3] + w1 * w1 * sm[6] + w2 * w2 * sm[8]
             + 2.f * (w0 * w1 * sm[4] + w0 * w2 * sm[5] + w1 * w2 * sm[7]);
    float var = q2 - mu0 * mu0;
    float sc = rsqrtf(fmaxf(var, 0.f) + 1e-5f) * g1[t];
    float mu = mu0 + b1[t] * 0.f;
    (void)mu;
    W1r[t] = make_float4(w0, w1, w2, b1[t]);
    prm[t] = make_float2(sc, be1[t] - (mu0 + 0.f) * sc);
  }
}

// ------- W split to MFMA-fragment-major layout (both weights in one launch) -----
__global__ void wsplit2(const float* __restrict__ W2, const float* __restrict__ W3,
                        unsigned short* __restrict__ Wf2, unsigned short* __restrict__ Wf3) {
  const float* W = blockIdx.y ? W3 : W2;
  unsigned short* Wf = blockIdx.y ? Wf3 : Wf2;
  int i = blockIdx.x * 256 + threadIdx.x;   // 16384 = 128x128
  if (i >= 128 * 128) return;
  int k = i >> 7, f = i & 127;
  float w = W[i];                            // W[k][f]
  unsigned short hi = f2bf(w);
  float hif = __uint_as_float((unsigned)hi << 16);
  unsigned short lo = f2bf(w - hif);
  int NT = f >> 4, l15 = f & 15, ks = k >> 5, lg = (k >> 3) & 3, j = k & 7;
  int lane = lg * 16 + l15;
  size_t base = ((size_t)(NT * 4 + ks) * 64 + lane) * 8 + j;
  Wf[base] = hi;
  Wf[16384 + base] = lo;
}

// ------ MFMA GEMM (swapped operands)
// MODE 1: BN+ReLU applied to bf16 A on load (layer 3)
// MODE 2: A computed on-the-fly from ag0 via fused lin1+BN+ReLU (layer 2)
template <int MODE>
__global__ __launch_bounds__(256) void gemm_mfma_t(const unsigned short* __restrict__ Abf,
                                                   const float4* __restrict__ ag0,
                                                   const float4* __restrict__ W1r,
                                                   const unsigned short* __restrict__ Wf,
                                                   const float* __restrict__ dinv,
                                                   const float2* __restrict__ prm,
                                                   unsigned short* __restrict__ C, int n) {
  int br = blockIdx.y;
  if (MODE == 1) Abf += (size_t)br * n * 128;
  if (MODE == 2) { ag0 += (size_t)br * n; W1r += (size_t)br * 128; }
  dinv += (size_t)br * n;
  C += (size_t)br * n * 128;
  prm += (size_t)br * 128;
  const int t = threadIdx.x;
  const int wave = t >> 6, lane = t & 63;
  const int l15 = lane & 15, lg = lane >> 4;
  const int row0 = blockIdx.x * 128 + wave * 32;
  const int n0 = row0 + l15, n1 = row0 + 16 + l15;
  const bf16x8* wfr = (const bf16x8*)Wf;       // hi frags [0..2047], lo at +2048
  float4 a0v = make_float4(0.f, 0.f, 0.f, 0.f), a1v = a0v;
  if (MODE == 2) {
    if (n0 < n) a0v = ag0[n0];
    if (n1 < n) a1v = ag0[n1];
  }
  f32x4 acc[8][2] = {};
#pragma unroll
  for (int ks = 0; ks < 4; ++ks) {
    int k0 = ks * 32 + lg * 8;
    bf16x8 nf0 = {}, nf1 = {};
    if (MODE == 1) {
      if (n0 < n) nf0 = *(const bf16x8*)&Abf[(size_t)n0 * 128 + k0];
      if (n1 < n) nf1 = *(const bf16x8*)&Abf[(size_t)n1 * 128 + k0];
      float4 pa = *(const float4*)&prm[k0];
      float4 pb = *(const float4*)&prm[k0 + 2];
      float4 pc = *(const float4*)&prm[k0 + 4];
      float4 pd = *(const float4*)&prm[k0 + 6];
      float scv[8] = {pa.x, pa.z, pb.x, pb.z, pc.x, pc.z, pd.x, pd.z};
      float ofv[8] = {pa.y, pa.w, pb.y, pb.w, pc.y, pc.w, pd.y, pd.w};
#pragma unroll
      for (int j = 0; j < 8; ++j) {
        float x0 = fmaxf(bf2f((unsigned short)nf0[j]) * scv[j] + ofv[j], 0.f);
        float x1 = fmaxf(bf2f((unsigned short)nf1[j]) * scv[j] + ofv[j], 0.f);
        nf0[j] = (short)f2bf(x0);
        nf1[j] = (short)f2bf(x1);
      }
    } else {   // MODE == 2: fused lin1+BN+ReLU from ag0
#pragma unroll
      for (int j = 0; j < 8; ++j) {
        int f = k0 + j;
        float4 wv = W1r[f];
        float2 p = prm[f];
        float x0 = (a0v.x * wv.x + a0v.y * wv.y + a0v.z * wv.z + wv.w) * p.x + p.y;
        float x1 = (a1v.x * wv.x + a1v.y * wv.y + a1v.z * wv.z + wv.w) * p.x + p.y;
        nf0[j] = (short)f2bf(fmaxf(x0, 0.f));
        nf1[j] = (short)f2bf(fmaxf(x1, 0.f));
      }
    }
#pragma unroll
    for (int NT = 0; NT < 8; ++NT) {
      bf16x8 wh = wfr[(NT * 4 + ks) * 64 + lane];
      bf16x8 wl = wfr[2048 + (NT * 4 + ks) * 64 + lane];
      acc[NT][0] = __builtin_amdgcn_mfma_f32_16x16x32_bf16(wh, nf0, acc[NT][0], 0, 0, 0);
      acc[NT][0] = __builtin_amdgcn_mfma_f32_16x16x32_bf16(wl, nf0, acc[NT][0], 0, 0, 0);
      acc[NT][1] = __builtin_amdgcn_mfma_f32_16x16x32_bf16(wh, nf1, acc[NT][1], 0, 0, 0);
      acc[NT][1] = __builtin_amdgcn_mfma_f32_16x16x32_bf16(wl, nf1, acc[NT][1], 0, 0, 0);
    }
  }
  float sc0 = (n0 < n) ? dinv[n0] : 0.f;
  float sc1 = (n1 < n) ? dinv[n1] : 0.f;
#pragma unroll
  for (int ng = 0; ng < 2; ++ng) {
    int node = (ng == 0) ? n0 : n1;
    float sc = (ng == 0) ? sc0 : sc1;
    if (node < n) {
#pragma unroll
      for (int NT = 0; NT < 8; ++NT) {
        ushort4 o;
        o.x = f2bf(acc[NT][ng][0] * sc);
        o.y = f2bf(acc[NT][ng][1] * sc);
        o.z = f2bf(acc[NT][ng][2] * sc);
        o.w = f2bf(acc[NT][ng][3] * sc);
        *(ushort4*)&C[(size_t)node * 128 + NT * 16 + lg * 4] = o;
      }
    }
  }
}

// ------- layer-2 aggregation: bf16 out + fused per-block BN partial stats -------
__global__ __launch_bounds__(256) void agg128_l2(const unsigned short* __restrict__ h,
                                                 const int* __restrict__ rp,
                                                 const int* __restrict__ csr,
                                                 const float* __restrict__ dinv,
                                                 const float* __restrict__ bias,
                                                 unsigned short* __restrict__ outb,
                                                 float* __restrict__ mpart, int n, int e,
                                                 int nagg) {
  int br = blockIdx.y;
  h += (size_t)br * n * 128;
  rp += (size_t)br * (n + 1);
  csr += (size_t)br * e;
  dinv += (size_t)br * n;
  outb += (size_t)br * n * 128;
  mpart += (size_t)br * nagg * 256;
  int t = threadIdx.x;
  int node = blockIdx.x * 16 + (t >> 4);
  int lane = t & 15;
  bool valid = node < n;
  const uint4* hp = (const uint4*)h;
  float acc[8] = {0.f};
  if (valid) {
    acc8(acc, hp[(size_t)node * 16 + lane]);
    int e0 = rp[node], e1 = rp[node + 1];
    int ee = e0;
    for (; ee + 8 <= e1; ee += 8) {
      int s0 = csr[ee],     s1 = csr[ee + 1], s2 = csr[ee + 2], s3 = csr[ee + 3];
      int s4 = csr[ee + 4], s5 = csr[ee + 5], s6 = csr[ee + 6], s7 = csr[ee + 7];
      uint4 v0 = hp[(size_t)s0 * 16 + lane];
      uint4 v1 = hp[(size_t)s1 * 16 + lane];
      uint4 v2 = hp[(size_t)s2 * 16 + lane];
      uint4 v3 = hp[(size_t)s3 * 16 + lane];
      uint4 v4 = hp[(size_t)s4 * 16 + lane];
      uint4 v5 = hp[(size_t)s5 * 16 + lane];
      uint4 v6 = hp[(size_t)s6 * 16 + lane];
      uint4 v7 = hp[(size_t)s7 * 16 + lane];
      acc8(acc, v0); acc8(acc, v1); acc8(acc, v2); acc8(acc, v3);
      acc8(acc, v4); acc8(acc, v5); acc8(acc, v6); acc8(acc, v7);
    }
    for (; ee + 4 <= e1; ee += 4) {
      int s0 = csr[ee], s1 = csr[ee + 1], s2 = csr[ee + 2], s3 = csr[ee + 3];
      uint4 v0 = hp[(size_t)s0 * 16 + lane];
      uint4 v1 = hp[(size_t)s1 * 16 + lane];
      uint4 v2 = hp[(size_t)s2 * 16 + lane];
      uint4 v3 = hp[(size_t)s3 * 16 + lane];
      acc8(acc, v0); acc8(acc, v1); acc8(acc, v2); acc8(acc, v3);
    }
    for (; ee < e1; ++ee) acc8(acc, hp[(size_t)csr[ee] * 16 + lane]);
  }
  float v[8], sq[8];
  if (valid) {
    float dd = dinv[node];
    float4 bb0 = *(const float4*)&bias[lane * 8];
    float4 bb1 = *(const float4*)&bias[lane * 8 + 4];
    v[0] = acc[0] * dd + bb0.x; v[1] = acc[1] * dd + bb0.y;
    v[2] = acc[2] * dd + bb0.z; v[3] = acc[3] * dd + bb0.w;
    v[4] = acc[4] * dd + bb1.x; v[5] = acc[5] * dd + bb1.y;
    v[6] = acc[6] * dd + bb1.z; v[7] = acc[7] * dd + bb1.w;
    uint4 o;
    o.x = pack2(v[0], v[1]); o.y = pack2(v[2], v[3]);
    o.z = pack2(v[4], v[5]); o.w = pack2(v[6], v[7]);
    *(uint4*)&outb[(size_t)node * 128 + lane * 8] = o;
  } else {
#pragma unroll
    for (int j = 0; j < 8; ++j) v[j] = 0.f;
  }
#pragma unroll
  for (int j = 0; j < 8; ++j) sq[j] = v[j] * v[j];
#pragma unroll
  for (int j = 0; j < 8; ++j) {
    v[j] += __shfl_xor(v[j], 16);  v[j] += __shfl_xor(v[j], 32);
    sq[j] += __shfl_xor(sq[j], 16); sq[j] += __shfl_xor(sq[j], 32);
  }
  __shared__ float sred[4][16][16];
  int wave = t >> 6, wl = t & 63;
  if (wl < 16) {
#pragma unroll
    for (int j = 0; j < 8; ++j) {
      sred[wave][wl][j] = v[j];
      sred[wave][wl][8 + j] = sq[j];
    }
  }
  __syncthreads();
  {
    int f = t & 127;
    int j = (f & 7) + ((t >> 7) << 3);   // 0-7 sum, 8-15 sumsq
    float s = sred[0][f >> 3][j] + sred[1][f >> 3][j]
            + sred[2][f >> 3][j] + sred[3][f >> 3][j];
    mpart[(size_t)blockIdx.x * 256 + t] = s;
  }
}

// stage-1 reduce of BN partials
__global__ __launch_bounds__(256) void bnred1(const float* __restrict__ mpart, int nblk,
                                              float* __restrict__ spart) {
  int br = blockIdx.y;
  mpart += (size_t)br * nblk * 256;
  spart += (size_t)br * 128 * 256;
  int t = threadIdx.x, b = blockIdx.x;
  float loc = 0.f;
  for (int i = b; i < nblk; i += 128) loc += mpart[(size_t)i * 256 + t];
  spart[b * 256 + t] = loc;
}

// stage-2: fold partials, compute per-feature (scale, offset)
__global__ void bnprep2(const float* __restrict__ spart,
                        const float* __restrict__ gam, const float* __restrict__ bet,
                        float invn, float2* __restrict__ prm) {
  int br = blockIdx.y;
  spart += (size_t)br * 128 * 256;
  prm += (size_t)br * 128;
  int t = threadIdx.x;
  float loc = 0.f;
  for (int i = 0; i < 128; ++i) loc += spart[i * 256 + t];
  __shared__ float sm[256];
  sm[t] = loc;
  __syncthreads();
  if (t < 128) {
    float mu = sm[t] * invn;
    float var = sm[128 + t] * invn - mu * mu;
    float sc = rsqrtf(fmaxf(var, 0.f) + 1e-5f) * gam[t];
    prm[t] = make_float2(sc, bet[t] - mu * sc);
  }
}

// ------- layer-3 aggregation with fused mean-pool accumulation ------------------
__global__ __launch_bounds__(256) void agg128_l3_pool(const unsigned short* __restrict__ h,
                                                      const int* __restrict__ rp,
                                                      const int* __restrict__ csr,
                                                      const float* __restrict__ dinv,
                                                      const float* __restrict__ bias,
                                                      const int* __restrict__ batch0,
                                                      const int* __restrict__ batch1,
                                                      float* __restrict__ pooled,
                                                      int n, int e, int g) {
  int br = blockIdx.y;
  h += (size_t)br * n * 128;
  rp += (size_t)br * (n + 1);
  csr += (size_t)br * e;
  dinv += (size_t)br * n;
  const int* batch = br ? batch1 : batch0;
  pooled += (size_t)br * g * 128;
  int t = threadIdx.x;
  int node = blockIdx.x * 16 + (t >> 4);
  int lane = t & 15;
  bool valid = node < n;
  const uint4* hp = (const uint4*)h;
  float acc[8] = {0.f};
  if (valid) {
    acc8(acc, hp[(size_t)node * 16 + lane]);
    int e0 = rp[node], e1 = rp[node + 1];
    int ee = e0;
    for (; ee + 8 <= e1; ee += 8) {
      int s0 = csr[ee],     s1 = csr[ee + 1], s2 = csr[ee + 2], s3 = csr[ee + 3];
      int s4 = csr[ee + 4], s5 = csr[ee + 5], s6 = csr[ee + 6], s7 = csr[ee + 7];
      uint4 v0 = hp[(size_t)s0 * 16 + lane];
      uint4 v1 = hp[(size_t)s1 * 16 + lane];
      uint4 v2 = hp[(size_t)s2 * 16 + lane];
      uint4 v3 = hp[(size_t)s3 * 16 + lane];
      uint4 v4 = hp[(size_t)s4 * 16 + lane];
      uint4 v5 = hp[(size_t)s5 * 16 + lane];
      uint4 v6 = hp[(size_t)s6 * 16 + lane];
      uint4 v7 = hp[(size_t)s7 * 16 + lane];
      acc8(acc, v0); acc8(acc, v1); acc8(acc, v2); acc8(acc, v3);
      acc8(acc, v4); acc8(acc, v5); acc8(acc, v6); acc8(acc, v7);
    }
    for (; ee + 4 <= e1; ee += 4) {
      int s0 = csr[ee], s1 = csr[ee + 1], s2 = csr[ee + 2], s3 = csr[ee + 3];
      uint4 v0 = hp[(size_t)s0 * 16 + lane];
      uint4 v1 = hp[(size_t)s1 * 16 + lane];
      uint4 v2 = hp[(size_t)s2 * 16 + lane];
      uint4 v3 = hp[(size_t)s3 * 16 + lane];
      acc8(acc, v0); acc8(acc, v1); acc8(acc, v2); acc8(acc, v3);
    }
    for (; ee < e1; ++ee) acc8(acc, hp[(size_t)csr[ee] * 16 + lane]);
  }
  __shared__ float lds[16][128];
  __shared__ int lgid[16];
  int ng = t >> 4;
  if (valid) {
    float dd = dinv[node];
    float4 bb0 = *(const float4*)&bias[lane * 8];
    float4 bb1 = *(const float4*)&bias[lane * 8 + 4];
    float w0 = bf2f(f2bf(acc[0] * dd + bb0.x));
    float w1 = bf2f(f2bf(acc[1] * dd + bb0.y));
    float w2 = bf2f(f2bf(acc[2] * dd + bb0.z));
    float w3 = bf2f(f2bf(acc[3] * dd + bb0.w));
    float w4 = bf2f(f2bf(acc[4] * dd + bb1.x));
    float w5 = bf2f(f2bf(acc[5] * dd + bb1.y));
    float w6 = bf2f(f2bf(acc[6] * dd + bb1.z));
    float w7 = bf2f(f2bf(acc[7] * dd + bb1.w));
    lds[ng][lane * 8 + 0] = w0; lds[ng][lane * 8 + 1] = w1;
    lds[ng][lane * 8 + 2] = w2; lds[ng][lane * 8 + 3] = w3;
    lds[ng][lane * 8 + 4] = w4; lds[ng][lane * 8 + 5] = w5;
    lds[ng][lane * 8 + 6] = w6; lds[ng][lane * 8 + 7] = w7;
    if (lane == 0) lgid[ng] = batch[node];
  } else {
#pragma unroll
    for (int j = 0; j < 8; ++j) lds[ng][lane * 8 + j] = 0.f;
    if (lane == 0) lgid[ng] = -1;
  }
  __syncthreads();
  {
    int f = t & 127, half = t >> 7;
    int lo = half * 8, hi = lo + 8;
    float run = 0.f;
    int cur = lgid[lo];
    for (int k = lo; k < hi; ++k) {
      int gg = lgid[k];
      if (gg != cur) {
        if (cur >= 0 && run != 0.f) atomicAdd(&pooled[cur * 128 + f], run);
        run = 0.f;
        cur = gg;
      }
      run += lds[k][f];
    }
    if (cur >= 0 && run != 0.f) atomicAdd(&pooled[cur * 128 + f], run);
  }
}

// ---------------- MLP head + L2 normalize ----------------
__global__ void mlp_kernel(const float* __restrict__ pooled, const int* __restrict__ gstart,
                           const float* __restrict__ Wp1, const float* __restrict__ bp1,
                           const float* __restrict__ Wp2, const float* __restrict__ bp2,
                           float* __restrict__ out, int g) {
  int br = blockIdx.y;
  pooled += (size_t)br * g * 128;
  gstart += (size_t)br * (g + 1);
  out += (size_t)br * g * 512;
  int gg = blockIdx.x, t = threadIdx.x;
  __shared__ float pv[128], hid[128], ov[512], red[256];
  if (t < 128) {
    float cntf = (float)(gstart[gg + 1] - gstart[gg]);
    pv[t] = pooled[gg * 128 + t] / fmaxf(cntf, 1.0f);
  }
  __syncthreads();
  if (t < 128) {
    float a = bp1[t];
    for (int k = 0; k < 128; ++k) a += pv[k] * Wp1[k * 128 + t];
    hid[t] = fmaxf(a, 0.0f);
  }
  __syncthreads();
  for (int o = t; o < 512; o += 256) {
    float a = bp2[o];
    for (int k = 0; k < 128; ++k) a += hid[k] * Wp2[k * 512 + o];
    ov[o] = a;
  }
  __syncthreads();
  red[t] = ov[t] * ov[t] + ov[t + 256] * ov[t + 256];
  __syncthreads();
  for (int sdt = 128; sdt > 0; sdt >>= 1) {
    if (t < sdt) red[t] += red[t + sdt];
    __syncthreads();
  }
  float inv = 1.0f / fmaxf(sqrtf(red[0]), 1e-12f);
  for (int o = t; o < 512; o += 256) out[(size_t)gg * 512 + o] = ov[o] * inv;
}

// ---------------- host orchestration ----------------
extern "C" void kernel_launch(void* const* d_in, const int* in_sizes, int n_in,
                              void* d_out, int out_size, void* d_ws, size_t ws_size,
                              hipStream_t stream) {
  const int N = in_sizes[0] / 3;
  const int E = in_sizes[1] / 2;
  const int G = out_size / (2 * 512);
  const int NBUCK = (N + BUCKET_MASK) >> BUCKET_SHIFT;
  const int NB3 = (N + 255) / 256;
  const int NAGG = (N + 15) / 16;

  char* w = (char*)d_ws;
  auto alloc = [&](size_t bytes) -> void* {
    void* p = (void*)w;
    w += (bytes + 255) & ~(size_t)255;
    return p;
  };
  unsigned short* Abf      = (unsigned short*)alloc(2 * (size_t)N * 128 * 2);
  unsigned short* Bh       = (unsigned short*)alloc(2 * (size_t)N * 128 * 2);
  float*          dinv     = (float*)alloc(2 * (size_t)N * 4);
  float4*         xs       = (float4*)alloc(2 * (size_t)N * 16);
  float4*         ag0      = (float4*)alloc(2 * (size_t)N * 16);
  int*            rp       = (int*)alloc(2 * (size_t)(N + 1) * 4);
  int*            csr      = (int*)alloc(2 * (size_t)E * 4);
  int*            bucketed = (int*)alloc(2 * (size_t)E * 4);
  int*            bcnt     = (int*)alloc(2 * (size_t)NBUCK * 4);
  int*            bbase    = (int*)alloc(2 * (size_t)(NBUCK + 1) * 4);
  int*            bcur     = (int*)alloc(2 * (size_t)NBUCK * 4);
  int*            gstart   = (int*)alloc(2 * (size_t)(G + 1) * 4);
  float*          pooled   = (float*)alloc(2 * (size_t)G * 128 * 4);
  unsigned short* Wf2      = (unsigned short*)alloc(2 * 128 * 128 * 2);
  unsigned short* Wf3      = (unsigned short*)alloc(2 * 128 * 128 * 2);
  float*          mpart    = (float*)alloc(2 * (size_t)NB3 * 9 * 4);
  float*          mpart2   = (float*)alloc(2 * (size_t)NAGG * 256 * 4);
  float*          spart    = (float*)alloc(2 * (size_t)128 * 256 * 4);
  float4*         W1r      = (float4*)alloc(2 * 128 * 16);
  float2*         prm1     = (float2*)alloc(2 * 128 * 8);
  float2*         prm2     = (float2*)alloc(2 * 128 * 8);

  const float* x0    = (const float*)d_in[0];
  const int*   ei0   = (const int*)d_in[1];
  const int*   bat0  = (const int*)d_in[2];
  const float* x1    = (const float*)d_in[3];
  const int*   ei1   = (const int*)d_in[4];
  const int*   bat1  = (const int*)d_in[5];
  const float* W1  = (const float*)d_in[6];
  const float* b1  = (const float*)d_in[7];
  const float* W2  = (const float*)d_in[8];
  const float* b2  = (const float*)d_in[9];
  const float* W3  = (const float*)d_in[10];
  const float* b3  = (const float*)d_in[11];
  const float* g1  = (const float*)d_in[12];
  const float* be1 = (const float*)d_in[13];
  const float* g2  = (const float*)d_in[14];
  const float* be2 = (const float*)d_in[15];
  const float* Wp1 = (const float*)d_in[16];
  const float* bp1 = (const float*)d_in[17];
  const float* Wp2 = (const float*)d_in[18];
  const float* bp2 = (const float*)d_in[19];

  const int* src0 = ei0;
  const int* dst0 = ei0 + E;
  const int* src1 = ei1;
  const int* dst1 = ei1 + E;
  float* outp = (float*)d_out;

  const int TB = 256;
  const int NTILE = (E + TILE - 1) / TILE;
  const float invn = 1.0f / (float)N;

  wsplit2<<<dim3(64, 2), TB, 0, stream>>>(W2, W3, Wf2, Wf3);

  // CSR build (both branches batched)
  zero_u32<<<(2 * NBUCK + TB - 1) / TB, TB, 0, stream>>>((unsigned*)bcnt, 2 * NBUCK);
  bucket_count<<<dim3(256, 2), TB, 0, stream>>>(dst0, dst1, bcnt, E, NBUCK);
  bucket_scan<<<dim3(1, 2), 1024, 0, stream>>>(bcnt, bbase, bcur, NBUCK);
  bucket_scatter<<<dim3(NTILE, 2), TB, 0, stream>>>(src0, dst0, src1, dst1, bcur, bucketed, E, NBUCK);
  bucket_to_csr<<<dim3(NBUCK, 2), TB, 0, stream>>>(bucketed, bbase, rp, dinv, csr, N, E, NBUCK);

  graph_bounds<<<dim3((N + TB - 1) / TB, 2), TB, 0, stream>>>(bat0, bat1, gstart, N, G);

  // layer 1 (lin1 is fused into the layer-2 GEMM)
  xs_scale<<<dim3((N + TB - 1) / TB, 2), TB, 0, stream>>>(x0, x1, dinv, xs, N);
  agg_f3<<<dim3(NB3, 2), TB, 0, stream>>>(xs, rp, csr, dinv, ag0, mpart, N, E, NB3);
  bnprep1<<<dim3(1, 2), TB, 0, stream>>>(mpart, NB3, W1, b1, g1, be1, invn, W1r, prm1);

  // layer 2: gemm (fused lin1+BN1+ReLU from ag0) -> agg (bf16 out + BN stats)
  gemm_mfma_t<2><<<dim3((N + 127) / 128, 2), TB, 0, stream>>>(nullptr, ag0, W1r, Wf2, dinv, prm1, Bh, N);
  agg128_l2<<<dim3(NAGG, 2), TB, 0, stream>>>(Bh, rp, csr, dinv, b2, Abf, mpart2, N, E, NAGG);
  bnred1<<<dim3(128, 2), TB, 0, stream>>>(mpart2, NAGG, spart);
  bnprep2<<<dim3(1, 2), TB, 0, stream>>>(spart, g2, be2, invn, prm2);

  // layer 3: gemm with BN2+ReLU fused on load -> agg with fused mean-pool
  gemm_mfma_t<1><<<dim3((N + 127) / 128, 2), TB, 0, stream>>>(Abf, nullptr, nullptr, Wf3, dinv, prm2, Bh, N);
  zero_u32<<<(2 * G * 128 + TB - 1) / TB, TB, 0, stream>>>((unsigned*)pooled, 2 * G * 128);
  agg128_l3_pool<<<dim3(NAGG, 2), TB, 0, stream>>>(Bh, rp, csr, dinv, b3, bat0, bat1, pooled, N, E, G);

  // head
  mlp_kernel<<<dim3(G, 2), TB, 0, stream>>>(pooled, gstart, Wp1, bp1, Wp2, bp2, outp, G);
}